// Round 7
// baseline (316.666 us; speedup 1.0000x reference)
//
#include <hip/hip_runtime.h>
#include <stdint.h>

#define N_RAYS  16384
#define T_STEPS 128
#define RPW   16            // rays per wave (= per block)
#define WAVES 8             // waves per block; wave w owns t in [16w, 16w+16)
#define TSEG  16

typedef _Float16 half8  __attribute__((ext_vector_type(8)));
typedef __fp16   fp16x2 __attribute__((ext_vector_type(2)));
typedef float    float4_ __attribute__((ext_vector_type(4)));
typedef uint32_t uint2_  __attribute__((ext_vector_type(2)));

// ws layout: half8-granular fragment tables, then fp32 bc2 pad.
#define H8_W1   0
#define H8_W2   256
#define H8_WC1  384
#define H8_WC2  640
#define BC2_F32_OFF 3072    // float index into ws (after 6144 halfs)

// pack two relu'd floats -> one dword of f16x2
__device__ __forceinline__ uint32_t pkr(float a, float b) {
    fp16x2 h = __builtin_amdgcn_cvt_pkrtz(fmaxf(a, 0.f), fmaxf(b, 0.f));
    return __builtin_bit_cast(uint32_t, h);
}
__device__ __forceinline__ uint32_t pk(float a, float b) {
    fp16x2 h = __builtin_amdgcn_cvt_pkrtz(a, b);
    return __builtin_bit_cast(uint32_t, h);
}

// ---------------------------------------------------------------------------
// prep: pack fp32 weights into f16 MFMA A-fragments (logic identical to the
// round-5 kernel that PASSED; re-gridded to 12 blocks for parallelism).
// ---------------------------------------------------------------------------
__global__ void prep_weights(const float* __restrict__ W1, const float* __restrict__ b1,
                             const float* __restrict__ W2, const float* __restrict__ b2,
                             const float* __restrict__ Wc1, const float* __restrict__ bc1,
                             const float* __restrict__ Wc2, const float* __restrict__ bc2,
                             void* __restrict__ ws) {
    _Float16* wh = (_Float16*)ws;
    float*    wf = (float*)ws;
    int fl = blockIdx.x * 64 + threadIdx.x;     // 12 blocks x 64 threads = 768
    if (fl < 12 * 64) {
        int frag = fl >> 6, lane = fl & 63;
        int mm = lane & 15, q = lane >> 4;
        if (frag < 4) {                       // W1^T tiles
            int tau = frag;
            int n = tau * 16 + mm;
            for (int j = 0; j < 8; ++j) {
                float w;
                if (j < 6)      w = W1[(3 + 6 * q + j) * 64 + n];
                else if (j == 6) w = (q == 0) ? W1[0 * 64 + n] : (q == 1) ? W1[2 * 64 + n] : 0.f;
                else             w = (q == 0) ? W1[1 * 64 + n] : (q == 1) ? b1[n] : 0.f;
                wh[(H8_W1 + tau * 64 + lane) * 8 + j] = (_Float16)w;
            }
        } else if (frag < 6) {                // W2^T
            int kap = frag - 4;
            for (int j = 0; j < 8; ++j) {
                int k = kap * 32 + q * 8 + j;
                wh[(H8_W2 + kap * 64 + lane) * 8 + j] = (_Float16)W2[k * 16 + mm];
            }
        } else if (frag < 10) {               // Wc1^T (permuted F slots)
            int tau = frag - 6;
            int nh = tau * 16 + mm;
            for (int j = 0; j < 8; ++j) {
                int s = q * 8 + j;
                float w;
                if (s == 0)       w = Wc1[15 * 64 + nh];
                else if (s <= 15) w = Wc1[(s - 1) * 64 + nh];
                else if (s <= 18) w = Wc1[s * 64 + nh];
                else if (s == 19) w = bc1[nh];
                else              w = 0.f;
                wh[(H8_WC1 + tau * 64 + lane) * 8 + j] = (_Float16)w;
            }
        } else {                              // Wc2^T
            int kap = frag - 10;
            for (int j = 0; j < 8; ++j) {
                int k = kap * 32 + q * 8 + j;
                wh[(H8_WC2 + kap * 64 + lane) * 8 + j] =
                    (_Float16)((mm < 3) ? Wc2[k * 3 + mm] : 0.f);
            }
        }
    }
    if (blockIdx.x == 0 && threadIdx.x < 16)
        wf[BC2_F32_OFF + threadIdx.x] = (threadIdx.x < 3) ? bc2[threadIdx.x] : 0.f;
}

// ---------------------------------------------------------------------------
// render. LDS stage layout: [chunk R (8 rows)][m (16 cols)][8 f16] -> 16B unit.
//   write (C-layout, tile tau): chunk 2*tau+(q>>1), +8B if (q&1)  -> 2-way banks (free)
//   read  (B-frag, chunk kap):  chunk 4*kap+q, full 16B           -> conflict-free
// Per-wave private slices; DS ops in-order within a wave -> no barriers in loop.
// ---------------------------------------------------------------------------
__global__ __launch_bounds__(512, 8)
void render_kernel(const float* __restrict__ rays_o, const float* __restrict__ rays_d,
                   const float* __restrict__ tnoise, const float* __restrict__ aabb,
                   const void* __restrict__ ws, float* __restrict__ out) {
    __shared__ __align__(16) _Float16 sH[WAVES][8 * 16 * 8];   // 2048 B / wave
    __shared__ __align__(16) _Float16 sF[WAVES][4 * 16 * 8];   // 1024 B / wave
    __shared__ float sComb[WAVES][RPW][5];

    const int tid  = threadIdx.x;
    const int wv   = tid >> 6;
    const int lane = tid & 63;
    const int m    = lane & 15;       // ray within block / sample col
    const int q    = lane >> 4;       // quad = K-chunk / freq group
    const int r    = blockIdx.x * RPW + m;

    // weight fragments -> registers (48 VGPRs)
    const half8* wsv = (const half8*)ws;
    half8 fW1[4], fW2[2], fWc1[4], fWc2[2];
    #pragma unroll
    for (int i = 0; i < 4; ++i) fW1[i]  = wsv[H8_W1  + i * 64 + lane];
    #pragma unroll
    for (int i = 0; i < 2; ++i) fW2[i]  = wsv[H8_W2  + i * 64 + lane];
    #pragma unroll
    for (int i = 0; i < 4; ++i) fWc1[i] = wsv[H8_WC1 + i * 64 + lane];
    #pragma unroll
    for (int i = 0; i < 2; ++i) fWc2[i] = wsv[H8_WC2 + i * 64 + lane];
    const float4_ binit = ((const float4_*)((const float*)ws + BC2_F32_OFF))[q];

    // per-ray setup
    float o0 = rays_o[r * 3 + 0], o1 = rays_o[r * 3 + 1], o2 = rays_o[r * 3 + 2];
    float d0 = rays_d[r * 3 + 0], d1 = rays_d[r * 3 + 1], d2 = rays_d[r * 3 + 2];
    float a00 = aabb[0], a01 = aabb[1], a02 = aabb[2];
    float a10 = aabb[3], a11 = aabb[4], a12 = aabb[5];

    float i0 = 1.0f / d0, i1 = 1.0f / d1, i2 = 1.0f / d2;
    float u0 = (a00 - o0) * i0, v0 = (a10 - o0) * i0;
    float u1 = (a01 - o1) * i1, v1 = (a11 - o1) * i1;
    float u2 = (a02 - o2) * i2, v2 = (a12 - o2) * i2;
    float tnear = fmaxf(fmaxf(fmaxf(fminf(u0, v0), fminf(u1, v1)), fminf(u2, v2)), 0.0f);
    float tfar  = fminf(fminf(fmaxf(u0, v0), fmaxf(u1, v1)), fmaxf(u2, v2));
    bool active = (tfar > tnear);
    float dt = tfar - tnear;

    float dn  = sqrtf(d0 * d0 + d1 * d1 + d2 * d2);
    float idn = 1.0f / dn;
    const float c0sh = 0.28209479177387814f;
    const float c1sh = 0.4886025119029199f;

    float sc0 = 2.0f / (a10 - a00), of0 = -a00 * sc0 - 1.0f;
    float sc1 = 2.0f / (a11 - a01), of1 = -a01 * sc1 - 1.0f;
    float sc2 = 2.0f / (a12 - a02), of2 = -a02 * sc2 - 1.0f;

    // loop-invariant LDS addresses
    _Float16* Hb = sH[wv];
    _Float16* Fb = sF[wv];
    _Float16*       hw  = &Hb[((q >> 1) * 16 + m) * 8 + 4 * (q & 1)];  // + tau*256
    const _Float16* hr  = &Hb[(q * 16 + m) * 8];                       // + kap*512
    _Float16*       fw  = &Fb[((q >> 1) * 16 + m) * 8 + 4 * (q & 1)];
    const _Float16* fr  = &Fb[(q * 16 + m) * 8];

    // F constant chunks (2: ynm/bias, 3: zeros) written once; same-lane reads later
    if (q == 2) {
        half8 c = {};
        c[0] = (_Float16)(c1sh * d1 * idn);
        c[1] = (_Float16)(c1sh * d2 * idn);
        c[2] = (_Float16)(c1sh * d0 * idn);
        c[3] = (_Float16)1.0f;
        *(half8*)fr = c;
    } else if (q == 3) {
        half8 z = {};
        *(half8*)fr = z;
    }

    const float fk = 3.14159265358979323846f * (float)(1 << q);
    const float4_ z4 = {0.f, 0.f, 0.f, 0.f};

    float trans = 1.0f, sdtot = 0.0f, wacc = 0.0f;
    float cacc0 = 0.0f, cacc1 = 0.0f, cacc2 = 0.0f;

    const int tbase = wv * TSEG;
    float n_cur = tnoise[tbase * N_RAYS + r];

    #pragma unroll 1
    for (int t = tbase; t < tbase + TSEG; ++t) {
        float n_nxt = (t < T_STEPS - 1) ? tnoise[(t + 1) * N_RAYS + r] : 0.0f;
        float ts  = fmaf(dt, ((float)t + n_cur) * (1.0f / 128.0f), tnear);
        float tsn = fmaf(dt, ((float)(t + 1) + n_nxt) * (1.0f / 128.0f), tnear);
        float delta = (t < T_STEPS - 1) ? (tsn - ts) : fmaf(tfar, 10.0f, -ts);
        n_cur = n_nxt;

        float xn0 = fmaf(fmaf(ts, d0, o0), sc0, of0);
        float xn1 = fmaf(fmaf(ts, d1, o1), sc1, of1);
        float xn2 = fmaf(fmaf(ts, d2, o2), sc2, of2);

        // B-fragment of X^T in-register
        float s0 = __sinf(fk * xn0), s1 = __sinf(fk * xn1), s2 = __sinf(fk * xn2);
        float cA = __cosf(fk * xn0), cB = __cosf(fk * xn1), cC = __cosf(fk * xn2);
        float e6 = (q == 0) ? xn0 : (q == 1) ? xn2 : 0.0f;
        float e7 = (q == 0) ? xn1 : (q == 1) ? 1.0f : 0.0f;
        union { uint32_t u[4]; half8 h; } xf_;
        xf_.u[0] = pk(s0, s1); xf_.u[1] = pk(s2, cA);
        xf_.u[2] = pk(cB, cC); xf_.u[3] = pk(e6, e7);
        half8 xf = xf_.h;

        // L1: 64 hidden neurons over 4 tiles
        float4_ h0 = __builtin_amdgcn_mfma_f32_16x16x32_f16(fW1[0], xf, z4, 0, 0, 0);
        float4_ h1 = __builtin_amdgcn_mfma_f32_16x16x32_f16(fW1[1], xf, z4, 0, 0, 0);
        float4_ h2 = __builtin_amdgcn_mfma_f32_16x16x32_f16(fW1[2], xf, z4, 0, 0, 0);
        float4_ h3 = __builtin_amdgcn_mfma_f32_16x16x32_f16(fW1[3], xf, z4, 0, 0, 0);

        // relu -> f16x2 dwords -> H stage (b64 stores, 2-way banks = free)
        {
            uint2_ w;
            w.x = pkr(h0.x, h0.y); w.y = pkr(h0.z, h0.w); *(uint2_*)(hw + 0 * 256) = w;
            w.x = pkr(h1.x, h1.y); w.y = pkr(h1.z, h1.w); *(uint2_*)(hw + 1 * 256) = w;
            w.x = pkr(h2.x, h2.y); w.y = pkr(h2.z, h2.w); *(uint2_*)(hw + 2 * 256) = w;
            w.x = pkr(h3.x, h3.y); w.y = pkr(h3.z, h3.w); *(uint2_*)(hw + 3 * 256) = w;
        }

        // L2: dh = W2^T @ H^T  (K=64)
        half8 hb0 = *(const half8*)(hr + 0);
        half8 hb1 = *(const half8*)(hr + 512);
        float4_ dh = __builtin_amdgcn_mfma_f32_16x16x32_f16(fW2[0], hb0, z4, 0, 0, 0);
        dh = __builtin_amdgcn_mfma_f32_16x16x32_f16(fW2[1], hb1, dh, 0, 0, 0);

        // F stage write (slot0 -> c0 const on q==0)
        {
            float f0 = (q == 0) ? c0sh : dh.x;
            uint2_ w;
            w.x = pk(f0, dh.y); w.y = pk(dh.z, dh.w);
            *(uint2_*)fw = w;
        }

        // C1: 64 color-hidden neurons, K=32
        half8 fb = *(const half8*)fr;
        float4_ g0 = __builtin_amdgcn_mfma_f32_16x16x32_f16(fWc1[0], fb, z4, 0, 0, 0);
        float4_ g1 = __builtin_amdgcn_mfma_f32_16x16x32_f16(fWc1[1], fb, z4, 0, 0, 0);
        float4_ g2 = __builtin_amdgcn_mfma_f32_16x16x32_f16(fWc1[2], fb, z4, 0, 0, 0);
        float4_ g3 = __builtin_amdgcn_mfma_f32_16x16x32_f16(fWc1[3], fb, z4, 0, 0, 0);

        {
            uint2_ w;
            w.x = pkr(g0.x, g0.y); w.y = pkr(g0.z, g0.w); *(uint2_*)(hw + 0 * 256) = w;
            w.x = pkr(g1.x, g1.y); w.y = pkr(g1.z, g1.w); *(uint2_*)(hw + 1 * 256) = w;
            w.x = pkr(g2.x, g2.y); w.y = pkr(g2.z, g2.w); *(uint2_*)(hw + 2 * 256) = w;
            w.x = pkr(g3.x, g3.y); w.y = pkr(g3.z, g3.w); *(uint2_*)(hw + 3 * 256) = w;
        }

        // C2: rgb = Wc2^T @ HC^T + bc2
        half8 cb0 = *(const half8*)(hr + 0);
        half8 cb1 = *(const half8*)(hr + 512);
        float4_ rgbp = __builtin_amdgcn_mfma_f32_16x16x32_f16(fWc2[0], cb0, binit, 0, 0, 0);
        rgbp = __builtin_amdgcn_mfma_f32_16x16x32_f16(fWc2[1], cb1, rgbp, 0, 0, 0);

        // volume-rendering step (meaningful on q==0 lanes)
        float sigma = __expf(dh.x);
        float sd = sigma * delta * dn;
        float e = __expf(-sd);
        float alpha = 1.0f - e;
        float w = trans * alpha;
        float rr = 1.0f / (1.0f + __expf(-rgbp.x));
        float rg = 1.0f / (1.0f + __expf(-rgbp.y));
        float rb = 1.0f / (1.0f + __expf(-rgbp.z));
        cacc0 = fmaf(w, rr, cacc0);
        cacc1 = fmaf(w, rg, cacc1);
        cacc2 = fmaf(w, rb, cacc2);
        wacc += w;
        trans *= e;
        sdtot += sd;
    }

    if (q == 0) {
        sComb[wv][m][0] = sdtot;
        sComb[wv][m][1] = wacc;
        sComb[wv][m][2] = cacc0;
        sComb[wv][m][3] = cacc1;
        sComb[wv][m][4] = cacc2;
    }
    __syncthreads();

    // cross-segment combine (thread tid<16 == wave-0 lane tid -> ray tid)
    if (tid < RPW) {
        float P = 1.0f, C0 = 0.0f, C1 = 0.0f, C2 = 0.0f, WS = 0.0f;
        #pragma unroll
        for (int s = 0; s < WAVES; ++s) {
            C0 = fmaf(P, sComb[s][tid][2], C0);
            C1 = fmaf(P, sComb[s][tid][3], C1);
            C2 = fmaf(P, sComb[s][tid][4], C2);
            WS = fmaf(P, sComb[s][tid][1], WS);
            P *= __expf(-sComb[s][tid][0]);
        }
        float act = active ? 1.0f : 0.0f;
        const int rg = blockIdx.x * RPW + tid;
        out[rg * 4 + 0] = C0 * act;
        out[rg * 4 + 1] = C1 * act;
        out[rg * 4 + 2] = C2 * act;
        out[rg * 4 + 3] = WS * act;
    }
}

extern "C" void kernel_launch(void* const* d_in, const int* in_sizes, int n_in,
                              void* d_out, int out_size, void* d_ws, size_t ws_size,
                              hipStream_t stream) {
    const float* rays_o = (const float*)d_in[0];
    const float* rays_d = (const float*)d_in[1];
    const float* tnoise = (const float*)d_in[2];
    const float* aabb   = (const float*)d_in[3];
    const float* W1  = (const float*)d_in[4];
    const float* b1  = (const float*)d_in[5];
    const float* W2  = (const float*)d_in[6];
    const float* b2  = (const float*)d_in[7];
    const float* Wc1 = (const float*)d_in[8];
    const float* bc1 = (const float*)d_in[9];
    const float* Wc2 = (const float*)d_in[10];
    const float* bc2 = (const float*)d_in[11];

    prep_weights<<<dim3(12), dim3(64), 0, stream>>>(W1, b1, W2, b2, Wc1, bc1, Wc2, bc2, d_ws);

    dim3 grid(N_RAYS / RPW);   // 1024 blocks
    dim3 block(WAVES * 64);    // 512 threads
    render_kernel<<<grid, block, 0, stream>>>(rays_o, rays_d, tnoise, aabb, d_ws,
                                              (float*)d_out);
}

// Round 8
// 140.129 us; speedup vs baseline: 2.2598x; 2.2598x over previous
//
#include <hip/hip_runtime.h>
#include <stdint.h>

#define N_RAYS  16384
#define T_STEPS 128
#define RPW   16            // rays per wave (= per block)
#define WAVES 8             // waves per block; wave w owns t in [16w, 16w+16)
#define TSEG  16

typedef _Float16 half8  __attribute__((ext_vector_type(8)));
typedef __fp16   fp16x2 __attribute__((ext_vector_type(2)));
typedef float    float4_ __attribute__((ext_vector_type(4)));
typedef uint32_t uint2_  __attribute__((ext_vector_type(2)));

// ws layout: half8-granular fragment tables, then fp32 bc2 pad.
#define H8_W1   0
#define H8_W2   256
#define H8_WC1  384
#define H8_WC2  640
#define BC2_F32_OFF 3072    // float index into ws (after 6144 halfs)

// pack two relu'd floats -> one dword of f16x2
__device__ __forceinline__ uint32_t pkr(float a, float b) {
    fp16x2 h = __builtin_amdgcn_cvt_pkrtz(fmaxf(a, 0.f), fmaxf(b, 0.f));
    return __builtin_bit_cast(uint32_t, h);
}
__device__ __forceinline__ uint32_t pk(float a, float b) {
    fp16x2 h = __builtin_amdgcn_cvt_pkrtz(a, b);
    return __builtin_bit_cast(uint32_t, h);
}

// ---------------------------------------------------------------------------
// prep: pack fp32 weights into f16 MFMA A-fragments.
// ---------------------------------------------------------------------------
__global__ void prep_weights(const float* __restrict__ W1, const float* __restrict__ b1,
                             const float* __restrict__ W2, const float* __restrict__ b2,
                             const float* __restrict__ Wc1, const float* __restrict__ bc1,
                             const float* __restrict__ Wc2, const float* __restrict__ bc2,
                             void* __restrict__ ws) {
    _Float16* wh = (_Float16*)ws;
    float*    wf = (float*)ws;
    int fl = blockIdx.x * 64 + threadIdx.x;     // 12 blocks x 64 threads = 768
    if (fl < 12 * 64) {
        int frag = fl >> 6, lane = fl & 63;
        int mm = lane & 15, q = lane >> 4;
        if (frag < 4) {                       // W1^T tiles
            int tau = frag;
            int n = tau * 16 + mm;
            for (int j = 0; j < 8; ++j) {
                float w;
                if (j < 6)      w = W1[(3 + 6 * q + j) * 64 + n];
                else if (j == 6) w = (q == 0) ? W1[0 * 64 + n] : (q == 1) ? W1[2 * 64 + n] : 0.f;
                else             w = (q == 0) ? W1[1 * 64 + n] : (q == 1) ? b1[n] : 0.f;
                wh[(H8_W1 + tau * 64 + lane) * 8 + j] = (_Float16)w;
            }
        } else if (frag < 6) {                // W2^T
            int kap = frag - 4;
            for (int j = 0; j < 8; ++j) {
                int k = kap * 32 + q * 8 + j;
                wh[(H8_W2 + kap * 64 + lane) * 8 + j] = (_Float16)W2[k * 16 + mm];
            }
        } else if (frag < 10) {               // Wc1^T (permuted F slots)
            int tau = frag - 6;
            int nh = tau * 16 + mm;
            for (int j = 0; j < 8; ++j) {
                int s = q * 8 + j;
                float w;
                if (s == 0)       w = Wc1[15 * 64 + nh];
                else if (s <= 15) w = Wc1[(s - 1) * 64 + nh];
                else if (s <= 18) w = Wc1[s * 64 + nh];
                else if (s == 19) w = bc1[nh];
                else              w = 0.f;
                wh[(H8_WC1 + tau * 64 + lane) * 8 + j] = (_Float16)w;
            }
        } else {                              // Wc2^T
            int kap = frag - 10;
            for (int j = 0; j < 8; ++j) {
                int k = kap * 32 + q * 8 + j;
                wh[(H8_WC2 + kap * 64 + lane) * 8 + j] =
                    (_Float16)((mm < 3) ? Wc2[k * 3 + mm] : 0.f);
            }
        }
    }
    if (blockIdx.x == 0 && threadIdx.x < 16)
        wf[BC2_F32_OFF + threadIdx.x] = (threadIdx.x < 3) ? bc2[threadIdx.x] : 0.f;
}

// ---------------------------------------------------------------------------
// render. LDS stage layout: [chunk R (8 rows)][m (16 cols)][8 f16] -> 16B unit.
// Per-wave private slices; DS ops in-order within a wave -> no barriers in loop.
// __launch_bounds__(512, 4): VGPR cap 128 — enough to keep the 48-VGPR weight
// fragment set resident (512,8 capped at 32 VGPR -> scratch spill -> 705 MB HBM).
// ---------------------------------------------------------------------------
__global__ __launch_bounds__(512, 4)
void render_kernel(const float* __restrict__ rays_o, const float* __restrict__ rays_d,
                   const float* __restrict__ tnoise, const float* __restrict__ aabb,
                   const void* __restrict__ ws, float* __restrict__ out) {
    __shared__ __align__(16) _Float16 sH[WAVES][8 * 16 * 8];   // 2048 B / wave
    __shared__ __align__(16) _Float16 sF[WAVES][4 * 16 * 8];   // 1024 B / wave
    __shared__ float sComb[WAVES][RPW][5];

    const int tid  = threadIdx.x;
    const int wv   = tid >> 6;
    const int lane = tid & 63;
    const int m    = lane & 15;       // ray within block / sample col
    const int q    = lane >> 4;       // quad = K-chunk / freq group
    const int r    = blockIdx.x * RPW + m;

    // weight fragments -> registers (48 VGPRs)
    const half8* wsv = (const half8*)ws;
    half8 fW1[4], fW2[2], fWc1[4], fWc2[2];
    #pragma unroll
    for (int i = 0; i < 4; ++i) fW1[i]  = wsv[H8_W1  + i * 64 + lane];
    #pragma unroll
    for (int i = 0; i < 2; ++i) fW2[i]  = wsv[H8_W2  + i * 64 + lane];
    #pragma unroll
    for (int i = 0; i < 4; ++i) fWc1[i] = wsv[H8_WC1 + i * 64 + lane];
    #pragma unroll
    for (int i = 0; i < 2; ++i) fWc2[i] = wsv[H8_WC2 + i * 64 + lane];
    const float4_ binit = ((const float4_*)((const float*)ws + BC2_F32_OFF))[q];

    // per-ray setup
    float o0 = rays_o[r * 3 + 0], o1 = rays_o[r * 3 + 1], o2 = rays_o[r * 3 + 2];
    float d0 = rays_d[r * 3 + 0], d1 = rays_d[r * 3 + 1], d2 = rays_d[r * 3 + 2];
    float a00 = aabb[0], a01 = aabb[1], a02 = aabb[2];
    float a10 = aabb[3], a11 = aabb[4], a12 = aabb[5];

    float i0 = 1.0f / d0, i1 = 1.0f / d1, i2 = 1.0f / d2;
    float u0 = (a00 - o0) * i0, v0 = (a10 - o0) * i0;
    float u1 = (a01 - o1) * i1, v1 = (a11 - o1) * i1;
    float u2 = (a02 - o2) * i2, v2 = (a12 - o2) * i2;
    float tnear = fmaxf(fmaxf(fmaxf(fminf(u0, v0), fminf(u1, v1)), fminf(u2, v2)), 0.0f);
    float tfar  = fminf(fminf(fmaxf(u0, v0), fmaxf(u1, v1)), fmaxf(u2, v2));
    bool active = (tfar > tnear);
    float dt = tfar - tnear;

    float dn  = sqrtf(d0 * d0 + d1 * d1 + d2 * d2);
    float idn = 1.0f / dn;
    const float c0sh = 0.28209479177387814f;
    const float c1sh = 0.4886025119029199f;

    float sc0 = 2.0f / (a10 - a00), of0 = -a00 * sc0 - 1.0f;
    float sc1 = 2.0f / (a11 - a01), of1 = -a01 * sc1 - 1.0f;
    float sc2 = 2.0f / (a12 - a02), of2 = -a02 * sc2 - 1.0f;

    // loop-invariant LDS addresses
    _Float16* Hb = sH[wv];
    _Float16* Fb = sF[wv];
    _Float16*       hw  = &Hb[((q >> 1) * 16 + m) * 8 + 4 * (q & 1)];  // + tau*256
    const _Float16* hr  = &Hb[(q * 16 + m) * 8];                       // + kap*512
    _Float16*       fw  = &Fb[((q >> 1) * 16 + m) * 8 + 4 * (q & 1)];
    const _Float16* fr  = &Fb[(q * 16 + m) * 8];

    // F constant chunks (2: ynm/bias, 3: zeros) written once; same-lane reads later
    if (q == 2) {
        half8 c = {};
        c[0] = (_Float16)(c1sh * d1 * idn);
        c[1] = (_Float16)(c1sh * d2 * idn);
        c[2] = (_Float16)(c1sh * d0 * idn);
        c[3] = (_Float16)1.0f;
        *(half8*)fr = c;
    } else if (q == 3) {
        half8 z = {};
        *(half8*)fr = z;
    }

    const float fk = 3.14159265358979323846f * (float)(1 << q);
    const float4_ z4 = {0.f, 0.f, 0.f, 0.f};

    float trans = 1.0f, sdtot = 0.0f, wacc = 0.0f;
    float cacc0 = 0.0f, cacc1 = 0.0f, cacc2 = 0.0f;

    const int tbase = wv * TSEG;
    float n_cur = tnoise[tbase * N_RAYS + r];

    #pragma unroll 1
    for (int t = tbase; t < tbase + TSEG; ++t) {
        float n_nxt = (t < T_STEPS - 1) ? tnoise[(t + 1) * N_RAYS + r] : 0.0f;
        float ts  = fmaf(dt, ((float)t + n_cur) * (1.0f / 128.0f), tnear);
        float tsn = fmaf(dt, ((float)(t + 1) + n_nxt) * (1.0f / 128.0f), tnear);
        float delta = (t < T_STEPS - 1) ? (tsn - ts) : fmaf(tfar, 10.0f, -ts);
        n_cur = n_nxt;

        float xn0 = fmaf(fmaf(ts, d0, o0), sc0, of0);
        float xn1 = fmaf(fmaf(ts, d1, o1), sc1, of1);
        float xn2 = fmaf(fmaf(ts, d2, o2), sc2, of2);

        // B-fragment of X^T in-register
        float s0 = __sinf(fk * xn0), s1 = __sinf(fk * xn1), s2 = __sinf(fk * xn2);
        float cA = __cosf(fk * xn0), cB = __cosf(fk * xn1), cC = __cosf(fk * xn2);
        float e6 = (q == 0) ? xn0 : (q == 1) ? xn2 : 0.0f;
        float e7 = (q == 0) ? xn1 : (q == 1) ? 1.0f : 0.0f;
        union { uint32_t u[4]; half8 h; } xf_;
        xf_.u[0] = pk(s0, s1); xf_.u[1] = pk(s2, cA);
        xf_.u[2] = pk(cB, cC); xf_.u[3] = pk(e6, e7);
        half8 xf = xf_.h;

        // L1: 64 hidden neurons over 4 tiles
        float4_ h0 = __builtin_amdgcn_mfma_f32_16x16x32_f16(fW1[0], xf, z4, 0, 0, 0);
        float4_ h1 = __builtin_amdgcn_mfma_f32_16x16x32_f16(fW1[1], xf, z4, 0, 0, 0);
        float4_ h2 = __builtin_amdgcn_mfma_f32_16x16x32_f16(fW1[2], xf, z4, 0, 0, 0);
        float4_ h3 = __builtin_amdgcn_mfma_f32_16x16x32_f16(fW1[3], xf, z4, 0, 0, 0);

        // relu -> f16x2 dwords -> H stage (b64 stores)
        {
            uint2_ w;
            w.x = pkr(h0.x, h0.y); w.y = pkr(h0.z, h0.w); *(uint2_*)(hw + 0 * 256) = w;
            w.x = pkr(h1.x, h1.y); w.y = pkr(h1.z, h1.w); *(uint2_*)(hw + 1 * 256) = w;
            w.x = pkr(h2.x, h2.y); w.y = pkr(h2.z, h2.w); *(uint2_*)(hw + 2 * 256) = w;
            w.x = pkr(h3.x, h3.y); w.y = pkr(h3.z, h3.w); *(uint2_*)(hw + 3 * 256) = w;
        }

        // L2: dh = W2^T @ H^T  (K=64)
        half8 hb0 = *(const half8*)(hr + 0);
        half8 hb1 = *(const half8*)(hr + 512);
        float4_ dh = __builtin_amdgcn_mfma_f32_16x16x32_f16(fW2[0], hb0, z4, 0, 0, 0);
        dh = __builtin_amdgcn_mfma_f32_16x16x32_f16(fW2[1], hb1, dh, 0, 0, 0);

        // F stage write (slot0 -> c0 const on q==0)
        {
            float f0 = (q == 0) ? c0sh : dh.x;
            uint2_ w;
            w.x = pk(f0, dh.y); w.y = pk(dh.z, dh.w);
            *(uint2_*)fw = w;
        }

        // C1: 64 color-hidden neurons, K=32
        half8 fb = *(const half8*)fr;
        float4_ g0 = __builtin_amdgcn_mfma_f32_16x16x32_f16(fWc1[0], fb, z4, 0, 0, 0);
        float4_ g1 = __builtin_amdgcn_mfma_f32_16x16x32_f16(fWc1[1], fb, z4, 0, 0, 0);
        float4_ g2 = __builtin_amdgcn_mfma_f32_16x16x32_f16(fWc1[2], fb, z4, 0, 0, 0);
        float4_ g3 = __builtin_amdgcn_mfma_f32_16x16x32_f16(fWc1[3], fb, z4, 0, 0, 0);

        {
            uint2_ w;
            w.x = pkr(g0.x, g0.y); w.y = pkr(g0.z, g0.w); *(uint2_*)(hw + 0 * 256) = w;
            w.x = pkr(g1.x, g1.y); w.y = pkr(g1.z, g1.w); *(uint2_*)(hw + 1 * 256) = w;
            w.x = pkr(g2.x, g2.y); w.y = pkr(g2.z, g2.w); *(uint2_*)(hw + 2 * 256) = w;
            w.x = pkr(g3.x, g3.y); w.y = pkr(g3.z, g3.w); *(uint2_*)(hw + 3 * 256) = w;
        }

        // C2: rgb = Wc2^T @ HC^T + bc2
        half8 cb0 = *(const half8*)(hr + 0);
        half8 cb1 = *(const half8*)(hr + 512);
        float4_ rgbp = __builtin_amdgcn_mfma_f32_16x16x32_f16(fWc2[0], cb0, binit, 0, 0, 0);
        rgbp = __builtin_amdgcn_mfma_f32_16x16x32_f16(fWc2[1], cb1, rgbp, 0, 0, 0);

        // volume-rendering step (meaningful on q==0 lanes)
        float sigma = __expf(dh.x);
        float sd = sigma * delta * dn;
        float e = __expf(-sd);
        float alpha = 1.0f - e;
        float w = trans * alpha;
        float rr = 1.0f / (1.0f + __expf(-rgbp.x));
        float rg = 1.0f / (1.0f + __expf(-rgbp.y));
        float rb = 1.0f / (1.0f + __expf(-rgbp.z));
        cacc0 = fmaf(w, rr, cacc0);
        cacc1 = fmaf(w, rg, cacc1);
        cacc2 = fmaf(w, rb, cacc2);
        wacc += w;
        trans *= e;
        sdtot += sd;
    }

    if (q == 0) {
        sComb[wv][m][0] = sdtot;
        sComb[wv][m][1] = wacc;
        sComb[wv][m][2] = cacc0;
        sComb[wv][m][3] = cacc1;
        sComb[wv][m][4] = cacc2;
    }
    __syncthreads();

    // cross-segment combine (thread tid<16 == wave-0 lane tid -> ray tid)
    if (tid < RPW) {
        float P = 1.0f, C0 = 0.0f, C1 = 0.0f, C2 = 0.0f, WS = 0.0f;
        #pragma unroll
        for (int s = 0; s < WAVES; ++s) {
            C0 = fmaf(P, sComb[s][tid][2], C0);
            C1 = fmaf(P, sComb[s][tid][3], C1);
            C2 = fmaf(P, sComb[s][tid][4], C2);
            WS = fmaf(P, sComb[s][tid][1], WS);
            P *= __expf(-sComb[s][tid][0]);
        }
        float act = active ? 1.0f : 0.0f;
        const int rg = blockIdx.x * RPW + tid;
        out[rg * 4 + 0] = C0 * act;
        out[rg * 4 + 1] = C1 * act;
        out[rg * 4 + 2] = C2 * act;
        out[rg * 4 + 3] = WS * act;
    }
}

extern "C" void kernel_launch(void* const* d_in, const int* in_sizes, int n_in,
                              void* d_out, int out_size, void* d_ws, size_t ws_size,
                              hipStream_t stream) {
    const float* rays_o = (const float*)d_in[0];
    const float* rays_d = (const float*)d_in[1];
    const float* tnoise = (const float*)d_in[2];
    const float* aabb   = (const float*)d_in[3];
    const float* W1  = (const float*)d_in[4];
    const float* b1  = (const float*)d_in[5];
    const float* W2  = (const float*)d_in[6];
    const float* b2  = (const float*)d_in[7];
    const float* Wc1 = (const float*)d_in[8];
    const float* bc1 = (const float*)d_in[9];
    const float* Wc2 = (const float*)d_in[10];
    const float* bc2 = (const float*)d_in[11];

    prep_weights<<<dim3(12), dim3(64), 0, stream>>>(W1, b1, W2, b2, Wc1, bc1, Wc2, bc2, d_ws);

    dim3 grid(N_RAYS / RPW);   // 1024 blocks
    dim3 block(WAVES * 64);    // 512 threads
    render_kernel<<<grid, block, 0, stream>>>(rays_o, rays_d, tnoise, aabb, d_ws,
                                              (float*)d_out);
}

// Round 10
// 124.242 us; speedup vs baseline: 2.5488x; 1.1279x over previous
//
#include <hip/hip_runtime.h>
#include <stdint.h>

#define N_RAYS  16384
#define T_STEPS 128
#define RPW   16            // rays per wave (= per block)
#define WAVES 8             // waves per block; wave w owns t in [16w, 16w+16)
#define TSEG  16

typedef _Float16 half8  __attribute__((ext_vector_type(8)));
typedef __fp16   fp16x2 __attribute__((ext_vector_type(2)));
typedef float    float4_ __attribute__((ext_vector_type(4)));
typedef uint32_t uint2_  __attribute__((ext_vector_type(2)));

// ws layout: half8-granular fragment tables, then fp32 bc2 pad.
#define H8_W1   0
#define H8_W2   256
#define H8_WC1  384
#define H8_WC2  640
#define BC2_F32_OFF 3072    // float index into ws (after 6144 halfs)

__device__ __forceinline__ uint32_t pk(float a, float b) {
    fp16x2 h = __builtin_amdgcn_cvt_pkrtz(a, b);
    return __builtin_bit_cast(uint32_t, h);
}
// pack two floats -> f16x2 dword, then packed relu (v_pk_max_f16)
__device__ __forceinline__ uint32_t pkr(float a, float b) {
    fp16x2 h = __builtin_amdgcn_cvt_pkrtz(a, b);
    fp16x2 z = {(__fp16)0.f, (__fp16)0.f};
    fp16x2 m = __builtin_elementwise_max(h, z);
    return __builtin_bit_cast(uint32_t, m);
}

// ---------------------------------------------------------------------------
// prep: pack fp32 weights into f16 MFMA A-fragments (unchanged, passing).
// ---------------------------------------------------------------------------
__global__ void prep_weights(const float* __restrict__ W1, const float* __restrict__ b1,
                             const float* __restrict__ W2, const float* __restrict__ b2,
                             const float* __restrict__ Wc1, const float* __restrict__ bc1,
                             const float* __restrict__ Wc2, const float* __restrict__ bc2,
                             void* __restrict__ ws) {
    _Float16* wh = (_Float16*)ws;
    float*    wf = (float*)ws;
    int fl = blockIdx.x * 64 + threadIdx.x;     // 12 blocks x 64 threads
    if (fl < 12 * 64) {
        int frag = fl >> 6, lane = fl & 63;
        int mm = lane & 15, q = lane >> 4;
        if (frag < 4) {                       // W1^T tiles
            int tau = frag;
            int n = tau * 16 + mm;
            for (int j = 0; j < 8; ++j) {
                float w;
                if (j < 6)      w = W1[(3 + 6 * q + j) * 64 + n];
                else if (j == 6) w = (q == 0) ? W1[0 * 64 + n] : (q == 1) ? W1[2 * 64 + n] : 0.f;
                else             w = (q == 0) ? W1[1 * 64 + n] : (q == 1) ? b1[n] : 0.f;
                wh[(H8_W1 + tau * 64 + lane) * 8 + j] = (_Float16)w;
            }
        } else if (frag < 6) {                // W2^T
            int kap = frag - 4;
            for (int j = 0; j < 8; ++j) {
                int k = kap * 32 + q * 8 + j;
                wh[(H8_W2 + kap * 64 + lane) * 8 + j] = (_Float16)W2[k * 16 + mm];
            }
        } else if (frag < 10) {               // Wc1^T (permuted F slots)
            int tau = frag - 6;
            int nh = tau * 16 + mm;
            for (int j = 0; j < 8; ++j) {
                int s = q * 8 + j;
                float w;
                if (s == 0)       w = Wc1[15 * 64 + nh];
                else if (s <= 15) w = Wc1[(s - 1) * 64 + nh];
                else if (s <= 18) w = Wc1[s * 64 + nh];
                else if (s == 19) w = bc1[nh];
                else              w = 0.f;
                wh[(H8_WC1 + tau * 64 + lane) * 8 + j] = (_Float16)w;
            }
        } else {                              // Wc2^T
            int kap = frag - 10;
            for (int j = 0; j < 8; ++j) {
                int k = kap * 32 + q * 8 + j;
                wh[(H8_WC2 + kap * 64 + lane) * 8 + j] =
                    (_Float16)((mm < 3) ? Wc2[k * 3 + mm] : 0.f);
            }
        }
    }
    if (blockIdx.x == 0 && threadIdx.x < 16)
        wf[BC2_F32_OFF + threadIdx.x] = (threadIdx.x < 3) ? bc2[threadIdx.x] : 0.f;
}

// ---------------------------------------------------------------------------
// render: 2-deep software pipeline over t (phases p=0,1 with private LDS
// buffers) so every LDS write->read RAW is covered by the other phase's work.
// ---------------------------------------------------------------------------
__global__ __launch_bounds__(512, 3)
void render_kernel(const float* __restrict__ rays_o, const float* __restrict__ rays_d,
                   const float* __restrict__ tnoise, const float* __restrict__ aabb,
                   const void* __restrict__ ws, float* __restrict__ out) {
    __shared__ __align__(16) _Float16 sH[WAVES][2][1024];   // 2 KB per buf
    __shared__ __align__(16) _Float16 sF[WAVES][2][512];    // 1 KB per buf
    __shared__ float sComb[WAVES][RPW][5];

    const int tid  = threadIdx.x;
    const int wv   = tid >> 6;
    const int lane = tid & 63;
    const int m    = lane & 15;       // ray within block / sample col
    const int q    = lane >> 4;       // quad = K-chunk / freq group
    const int r    = blockIdx.x * RPW + m;

    // weight fragments -> registers
    const half8* wsv = (const half8*)ws;
    half8 fW1[4], fW2[2], fWc1[4], fWc2[2];
    #pragma unroll
    for (int i = 0; i < 4; ++i) fW1[i]  = wsv[H8_W1  + i * 64 + lane];
    #pragma unroll
    for (int i = 0; i < 2; ++i) fW2[i]  = wsv[H8_W2  + i * 64 + lane];
    #pragma unroll
    for (int i = 0; i < 4; ++i) fWc1[i] = wsv[H8_WC1 + i * 64 + lane];
    #pragma unroll
    for (int i = 0; i < 2; ++i) fWc2[i] = wsv[H8_WC2 + i * 64 + lane];
    const float4_ binit = ((const float4_*)((const float*)ws + BC2_F32_OFF))[q];

    // per-ray setup
    float o0 = rays_o[r * 3 + 0], o1 = rays_o[r * 3 + 1], o2 = rays_o[r * 3 + 2];
    float d0 = rays_d[r * 3 + 0], d1 = rays_d[r * 3 + 1], d2 = rays_d[r * 3 + 2];
    float a00 = aabb[0], a01 = aabb[1], a02 = aabb[2];
    float a10 = aabb[3], a11 = aabb[4], a12 = aabb[5];

    float i0 = 1.0f / d0, i1 = 1.0f / d1, i2 = 1.0f / d2;
    float u0 = (a00 - o0) * i0, v0 = (a10 - o0) * i0;
    float u1 = (a01 - o1) * i1, v1 = (a11 - o1) * i1;
    float u2 = (a02 - o2) * i2, v2 = (a12 - o2) * i2;
    float tnear = fmaxf(fmaxf(fmaxf(fminf(u0, v0), fminf(u1, v1)), fminf(u2, v2)), 0.0f);
    float tfar  = fminf(fminf(fmaxf(u0, v0), fmaxf(u1, v1)), fmaxf(u2, v2));
    bool active = (tfar > tnear);
    float dt = tfar - tnear;
    float dt128 = dt * (1.0f / 128.0f);

    float dn  = sqrtf(d0 * d0 + d1 * d1 + d2 * d2);
    float idn = 1.0f / dn;
    const float c0sh = 0.28209479177387814f;
    const float c1sh = 0.4886025119029199f;

    // xn in revolutions domain: r_q = 2^(q-1) * xn  (so v_sin(r_q)=sin(pi 2^q xn))
    float qs = 0.5f * (float)(1 << q);
    float sc0 = 2.0f / (a10 - a00), of0 = -a00 * sc0 - 1.0f;
    float sc1 = 2.0f / (a11 - a01), of1 = -a01 * sc1 - 1.0f;
    float sc2 = 2.0f / (a12 - a02), of2 = -a02 * sc2 - 1.0f;
    float scq0 = sc0 * qs, ofq0 = of0 * qs;
    float scq1 = sc1 * qs, ofq1 = of1 * qs;
    float scq2 = sc2 * qs, ofq2 = of2 * qs;

    // loop-invariant LDS addresses, per phase
    _Float16*       hwp[2];
    const _Float16* hrp[2];
    _Float16*       fwp[2];
    const _Float16* frp[2];
    #pragma unroll
    for (int p = 0; p < 2; ++p) {
        hwp[p] = &sH[wv][p][((q >> 1) * 16 + m) * 8 + 4 * (q & 1)];  // + tau*256
        hrp[p] = &sH[wv][p][(q * 16 + m) * 8];                       // + kap*512
        fwp[p] = &sF[wv][p][((q >> 1) * 16 + m) * 8 + 4 * (q & 1)];
        frp[p] = &sF[wv][p][(q * 16 + m) * 8];
    }

    // F constant chunks (2: ynm/bias, 3: zeros) in BOTH phase buffers
    if (q == 2) {
        half8 c = {};
        c[0] = (_Float16)(c1sh * d1 * idn);
        c[1] = (_Float16)(c1sh * d2 * idn);
        c[2] = (_Float16)(c1sh * d0 * idn);
        c[3] = (_Float16)1.0f;
        *(half8*)frp[0] = c;
        *(half8*)frp[1] = c;
    } else if (q == 3) {
        half8 z = {};
        *(half8*)frp[0] = z;
        *(half8*)frp[1] = z;
    }

    const float4_ z4 = {0.f, 0.f, 0.f, 0.f};
    const bool q0 = (q == 0), q1 = (q == 1);

    float trans = 1.0f, sdtot = 0.0f, wacc = 0.0f;
    float cacc0 = 0.0f, cacc1 = 0.0f, cacc2 = 0.0f;

    const int tbase = wv * TSEG;
    float nA = tnoise[(tbase + 0) * N_RAYS + r];
    float nB = tnoise[(tbase + 1) * N_RAYS + r];

    #pragma unroll 1
    for (int tt = 0; tt < TSEG; tt += 2) {
        const int t0 = tbase + tt, t1 = t0 + 1;
        float nC = (t0 + 2 < T_STEPS) ? tnoise[(t0 + 2) * N_RAYS + r] : 0.0f;
        float nD = (t0 + 3 < T_STEPS) ? tnoise[(t0 + 3) * N_RAYS + r] : 0.0f;
        float ts0 = fmaf((float)t0 + nA, dt128, tnear);
        float ts1 = fmaf((float)t1 + nB, dt128, tnear);
        float ts2 = fmaf((float)(t0 + 2) + nC, dt128, tnear);
        float tsP[2]    = {ts0, ts1};
        float deltaP[2];
        deltaP[0] = ts1 - ts0;
        deltaP[1] = (t1 < T_STEPS - 1) ? (ts2 - ts1) : fmaf(tfar, 10.0f, -ts1);
        nA = nC; nB = nD;

        float4_ dhP[2], rgbP[2];

        // ---- FRONT (both phases): posenc -> L1 -> relu/pack -> write H[p] ----
        #pragma unroll
        for (int p = 0; p < 2; ++p) {
            float x = fmaf(tsP[p], d0, o0);
            float y = fmaf(tsP[p], d1, o1);
            float z = fmaf(tsP[p], d2, o2);
            float xr0 = fmaf(x, scq0, ofq0);   // 2^(q-1) * xn0
            float xr1 = fmaf(y, scq1, ofq1);
            float xr2 = fmaf(z, scq2, ofq2);
            float s0 = __builtin_amdgcn_sinf(xr0);
            float s1 = __builtin_amdgcn_sinf(xr1);
            float s2 = __builtin_amdgcn_sinf(xr2);
            float cA = __builtin_amdgcn_cosf(xr0);
            float cB = __builtin_amdgcn_cosf(xr1);
            float cC = __builtin_amdgcn_cosf(xr2);
            float e6 = q0 ? (xr0 + xr0) : (q1 ? xr2 : 0.0f);
            float e7 = q0 ? (xr1 + xr1) : (q1 ? 1.0f : 0.0f);
            union { uint32_t u[4]; half8 h; } xf_;
            xf_.u[0] = pk(s0, s1); xf_.u[1] = pk(s2, cA);
            xf_.u[2] = pk(cB, cC); xf_.u[3] = pk(e6, e7);
            half8 xf = xf_.h;

            float4_ h0 = __builtin_amdgcn_mfma_f32_16x16x32_f16(fW1[0], xf, z4, 0, 0, 0);
            float4_ h1 = __builtin_amdgcn_mfma_f32_16x16x32_f16(fW1[1], xf, z4, 0, 0, 0);
            float4_ h2 = __builtin_amdgcn_mfma_f32_16x16x32_f16(fW1[2], xf, z4, 0, 0, 0);
            float4_ h3 = __builtin_amdgcn_mfma_f32_16x16x32_f16(fW1[3], xf, z4, 0, 0, 0);
            uint2_ w;
            w.x = pkr(h0.x, h0.y); w.y = pkr(h0.z, h0.w); *(uint2_*)(hwp[p] + 0 * 256) = w;
            w.x = pkr(h1.x, h1.y); w.y = pkr(h1.z, h1.w); *(uint2_*)(hwp[p] + 1 * 256) = w;
            w.x = pkr(h2.x, h2.y); w.y = pkr(h2.z, h2.w); *(uint2_*)(hwp[p] + 2 * 256) = w;
            w.x = pkr(h3.x, h3.y); w.y = pkr(h3.z, h3.w); *(uint2_*)(hwp[p] + 3 * 256) = w;
        }

        // ---- MID: read H[p] -> L2 -> dh -> write F[p] ----
        #pragma unroll
        for (int p = 0; p < 2; ++p) {
            half8 hb0 = *(const half8*)(hrp[p] + 0);
            half8 hb1 = *(const half8*)(hrp[p] + 512);
            float4_ dh = __builtin_amdgcn_mfma_f32_16x16x32_f16(fW2[0], hb0, z4, 0, 0, 0);
            dh = __builtin_amdgcn_mfma_f32_16x16x32_f16(fW2[1], hb1, dh, 0, 0, 0);
            dhP[p] = dh;
            float f0 = q0 ? c0sh : dh.x;
            uint2_ w;
            w.x = pk(f0, dh.y); w.y = pk(dh.z, dh.w);
            *(uint2_*)fwp[p] = w;
        }

        // ---- BACK: read F[p] -> C1 -> relu/pack -> write HC[p] (reuses H buf) ----
        #pragma unroll
        for (int p = 0; p < 2; ++p) {
            half8 fb = *(const half8*)frp[p];
            float4_ g0 = __builtin_amdgcn_mfma_f32_16x16x32_f16(fWc1[0], fb, z4, 0, 0, 0);
            float4_ g1 = __builtin_amdgcn_mfma_f32_16x16x32_f16(fWc1[1], fb, z4, 0, 0, 0);
            float4_ g2 = __builtin_amdgcn_mfma_f32_16x16x32_f16(fWc1[2], fb, z4, 0, 0, 0);
            float4_ g3 = __builtin_amdgcn_mfma_f32_16x16x32_f16(fWc1[3], fb, z4, 0, 0, 0);
            uint2_ w;
            w.x = pkr(g0.x, g0.y); w.y = pkr(g0.z, g0.w); *(uint2_*)(hwp[p] + 0 * 256) = w;
            w.x = pkr(g1.x, g1.y); w.y = pkr(g1.z, g1.w); *(uint2_*)(hwp[p] + 1 * 256) = w;
            w.x = pkr(g2.x, g2.y); w.y = pkr(g2.z, g2.w); *(uint2_*)(hwp[p] + 2 * 256) = w;
            w.x = pkr(g3.x, g3.y); w.y = pkr(g3.z, g3.w); *(uint2_*)(hwp[p] + 3 * 256) = w;
        }

        // ---- FIN: read HC[p] -> C2 -> rgb logits ----
        #pragma unroll
        for (int p = 0; p < 2; ++p) {
            half8 cb0 = *(const half8*)(hrp[p] + 0);
            half8 cb1 = *(const half8*)(hrp[p] + 512);
            float4_ rgbp = __builtin_amdgcn_mfma_f32_16x16x32_f16(fWc2[0], cb0, binit, 0, 0, 0);
            rgbP[p] = __builtin_amdgcn_mfma_f32_16x16x32_f16(fWc2[1], cb1, rgbp, 0, 0, 0);
        }

        // ---- TAIL (q==0 lanes hold rows 0..3 = sigma/r/g/b), sequential scan ----
        if (q == 0) {
            #pragma unroll
            for (int p = 0; p < 2; ++p) {
                float sigma = __expf(dhP[p].x);
                float sd = sigma * deltaP[p] * dn;
                float e = __expf(-sd);
                float alpha = 1.0f - e;
                float w = trans * alpha;
                float rr = __builtin_amdgcn_rcpf(1.0f + __expf(-rgbP[p].x));
                float rg = __builtin_amdgcn_rcpf(1.0f + __expf(-rgbP[p].y));
                float rb = __builtin_amdgcn_rcpf(1.0f + __expf(-rgbP[p].z));
                cacc0 = fmaf(w, rr, cacc0);
                cacc1 = fmaf(w, rg, cacc1);
                cacc2 = fmaf(w, rb, cacc2);
                wacc += w;
                trans *= e;
                sdtot += sd;
            }
        }
    }

    if (q == 0) {
        sComb[wv][m][0] = sdtot;
        sComb[wv][m][1] = wacc;
        sComb[wv][m][2] = cacc0;
        sComb[wv][m][3] = cacc1;
        sComb[wv][m][4] = cacc2;
    }
    __syncthreads();

    // cross-segment combine
    if (tid < RPW) {
        float P = 1.0f, C0 = 0.0f, C1 = 0.0f, C2 = 0.0f, WS = 0.0f;
        #pragma unroll
        for (int s = 0; s < WAVES; ++s) {
            C0 = fmaf(P, sComb[s][tid][2], C0);
            C1 = fmaf(P, sComb[s][tid][3], C1);
            C2 = fmaf(P, sComb[s][tid][4], C2);
            WS = fmaf(P, sComb[s][tid][1], WS);
            P *= __expf(-sComb[s][tid][0]);
        }
        float act = active ? 1.0f : 0.0f;
        const int rg = blockIdx.x * RPW + tid;
        out[rg * 4 + 0] = C0 * act;
        out[rg * 4 + 1] = C1 * act;
        out[rg * 4 + 2] = C2 * act;
        out[rg * 4 + 3] = WS * act;
    }
}

extern "C" void kernel_launch(void* const* d_in, const int* in_sizes, int n_in,
                              void* d_out, int out_size, void* d_ws, size_t ws_size,
                              hipStream_t stream) {
    const float* rays_o = (const float*)d_in[0];
    const float* rays_d = (const float*)d_in[1];
    const float* tnoise = (const float*)d_in[2];
    const float* aabb   = (const float*)d_in[3];
    const float* W1  = (const float*)d_in[4];
    const float* b1  = (const float*)d_in[5];
    const float* W2  = (const float*)d_in[6];
    const float* b2  = (const float*)d_in[7];
    const float* Wc1 = (const float*)d_in[8];
    const float* bc1 = (const float*)d_in[9];
    const float* Wc2 = (const float*)d_in[10];
    const float* bc2 = (const float*)d_in[11];

    prep_weights<<<dim3(12), dim3(64), 0, stream>>>(W1, b1, W2, b2, Wc1, bc1, Wc2, bc2, d_ws);

    dim3 grid(N_RAYS / RPW);   // 1024 blocks
    dim3 block(WAVES * 64);    // 512 threads
    render_kernel<<<grid, block, 0, stream>>>(rays_o, rays_d, tnoise, aabb, d_ws,
                                              (float*)d_out);
}